// Round 1
// baseline (221.658 us; speedup 1.0000x reference)
//
#include <hip/hip_runtime.h>

// 5-level Db4 DWT, rows of 16384 fp32, B*C = 4096 rows.
// out layout (flat, return order):
//   Fd  4096x512   @ 0
//   Ft  4096x512   @ 2097152
//   Fa  4096x1024  @ 4194304
//   Fb  4096x2048  @ 8388608
//   Fg  4096x4096  @ 16777216
//   FR  4096x8192  @ 33554432   (per-row: [Fd|Ft|Fa|Fb|Fg])

static constexpr int SLEN = 16384;

__global__ __launch_bounds__(256)
void dwt5_kernel(const float* __restrict__ x,
                 const float* __restrict__ hF,
                 const float* __restrict__ gF,
                 float* __restrict__ out)
{
    __shared__ float bufA[8192];   // a1, later a3
    __shared__ float bufB[4096];   // a2, later a4

    const int r   = blockIdx.x;
    const int tid = threadIdx.x;

    float h[8], g[8];
#pragma unroll
    for (int k = 0; k < 8; ++k) { h[k] = hF[k]; g[k] = gF[k]; }

    const float* __restrict__ xr = x + (size_t)r * SLEN;
    const size_t frBase = (size_t)33554432 + (size_t)r * 8192;

    // ---- Level 1: x(16384) -> a1(8192), LOW ONLY (d1 is never output) ----
    for (int n = tid; n < 8192; n += 256) {
        const int base = 2 * n - 7;
        float s = 0.f;
#pragma unroll
        for (int k = 0; k < 8; ++k) {
            int m = base + k;
            m = (m < 0) ? -m : m;      // reflect-pad left
            s = fmaf(h[k], xr[m], s);
        }
        bufA[n] = s;
    }
    __syncthreads();

    // ---- Level 2: a1(8192) -> a2(4096) low, d2(4096) -> Fg + FR ----
    {
        float* __restrict__ hi1 = out + (size_t)16777216 + (size_t)r * 4096;
        float* __restrict__ hi2 = out + frBase + 4096;
        for (int n = tid; n < 4096; n += 256) {
            const int base = 2 * n - 7;
            float sl = 0.f, sh = 0.f;
#pragma unroll
            for (int k = 0; k < 8; ++k) {
                int m = base + k;
                m = (m < 0) ? -m : m;
                const float v = bufA[m];
                sl = fmaf(h[k], v, sl);
                sh = fmaf(g[k], v, sh);
            }
            bufB[n] = sl;
            hi1[n] = sh;
            hi2[n] = sh;
        }
    }
    __syncthreads();

    // ---- Level 3: a2(4096) -> a3(2048) low, d3(2048) -> Fb + FR ----
    {
        float* __restrict__ hi1 = out + (size_t)8388608 + (size_t)r * 2048;
        float* __restrict__ hi2 = out + frBase + 2048;
        for (int n = tid; n < 2048; n += 256) {
            const int base = 2 * n - 7;
            float sl = 0.f, sh = 0.f;
#pragma unroll
            for (int k = 0; k < 8; ++k) {
                int m = base + k;
                m = (m < 0) ? -m : m;
                const float v = bufB[m];
                sl = fmaf(h[k], v, sl);
                sh = fmaf(g[k], v, sh);
            }
            bufA[n] = sl;              // a3 reuses a1 space
            hi1[n] = sh;
            hi2[n] = sh;
        }
    }
    __syncthreads();

    // ---- Level 4: a3(2048) -> a4(1024) low, d4(1024) -> Fa + FR ----
    {
        float* __restrict__ hi1 = out + (size_t)4194304 + (size_t)r * 1024;
        float* __restrict__ hi2 = out + frBase + 1024;
        for (int n = tid; n < 1024; n += 256) {
            const int base = 2 * n - 7;
            float sl = 0.f, sh = 0.f;
#pragma unroll
            for (int k = 0; k < 8; ++k) {
                int m = base + k;
                m = (m < 0) ? -m : m;
                const float v = bufA[m];
                sl = fmaf(h[k], v, sl);
                sh = fmaf(g[k], v, sh);
            }
            bufB[n] = sl;              // a4 reuses a2 space
            hi1[n] = sh;
            hi2[n] = sh;
        }
    }
    __syncthreads();

    // ---- Level 5: a4(1024) -> Fd(512 low) + Ft(512 high), both also to FR ----
    {
        float* __restrict__ lo1 = out + (size_t)0        + (size_t)r * 512;
        float* __restrict__ lo2 = out + frBase + 0;
        float* __restrict__ hi1 = out + (size_t)2097152  + (size_t)r * 512;
        float* __restrict__ hi2 = out + frBase + 512;
        for (int n = tid; n < 512; n += 256) {
            const int base = 2 * n - 7;
            float sl = 0.f, sh = 0.f;
#pragma unroll
            for (int k = 0; k < 8; ++k) {
                int m = base + k;
                m = (m < 0) ? -m : m;
                const float v = bufB[m];
                sl = fmaf(h[k], v, sl);
                sh = fmaf(g[k], v, sh);
            }
            lo1[n] = sl;
            lo2[n] = sl;
            hi1[n] = sh;
            hi2[n] = sh;
        }
    }
}

extern "C" void kernel_launch(void* const* d_in, const int* in_sizes, int n_in,
                              void* d_out, int out_size, void* d_ws, size_t ws_size,
                              hipStream_t stream) {
    const float* x  = (const float*)d_in[0];
    const float* lo = (const float*)d_in[1];
    const float* hi = (const float*)d_in[2];
    float* out = (float*)d_out;

    dwt5_kernel<<<4096, 256, 0, stream>>>(x, lo, hi, out);
}

// Round 3
// 120.022 us; speedup vs baseline: 1.8468x; 1.8468x over previous
//
#include <hip/hip_runtime.h>

// 5-level Db4 DWT, rows of 16384 fp32, B*C = 4096 rows.
// out layout (flat, return order):
//   Fd  4096x512   @ 0
//   Ft  4096x512   @ 2097152
//   Fa  4096x1024  @ 4194304
//   Fb  4096x2048  @ 8388608
//   Fg  4096x4096  @ 16777216
//   FR  4096x8192  @ 33554432   (per-row: [Fd|Ft|Fa|Fb|Fg])

static constexpr int SLEN = 16384;

// Db4 filters are fixed (non-learnable) — hardcoded as literals.
__device__ __forceinline__ float dotH(const float* w) {
    float s =      -0.010597401785069032f * w[0];
    s = fmaf( 0.032883011666982945f, w[1], s);
    s = fmaf( 0.030841381835560764f, w[2], s);
    s = fmaf(-0.18703481171888114f,  w[3], s);
    s = fmaf(-0.02798376941698385f,  w[4], s);
    s = fmaf( 0.6308807679295904f,   w[5], s);
    s = fmaf( 0.7148465705529155f,   w[6], s);
    s = fmaf( 0.2303778133088964f,   w[7], s);
    return s;
}
// g[k] = (-1)^k * h[7-k]
__device__ __forceinline__ float dotG(const float* w) {
    float s =       0.2303778133088964f * w[0];
    s = fmaf(-0.7148465705529155f,   w[1], s);
    s = fmaf( 0.6308807679295904f,   w[2], s);
    s = fmaf( 0.02798376941698385f,  w[3], s);
    s = fmaf(-0.18703481171888114f,  w[4], s);
    s = fmaf(-0.030841381835560764f, w[5], s);
    s = fmaf( 0.032883011666982945f, w[6], s);   // FIXED: +h[1]
    s = fmaf( 0.010597401785069032f, w[7], s);
    return s;
}

// Load the 16-float window src[8q-8 .. 8q+7] for outputs n=4q..4q+3.
// q==0 takes the scalar reflect path (index m<0 -> -m).
__device__ __forceinline__ void loadw16(const float* __restrict__ src, int q, float* w) {
    if (q == 0) {
#pragma unroll
        for (int i = 0; i < 16; ++i) { int m = i - 8; m = (m < 0) ? -m : m; w[i] = src[m]; }
    } else {
        const float4 v0 = *(const float4*)(src + 8 * q - 8);
        const float4 v1 = *(const float4*)(src + 8 * q - 4);
        const float4 v2 = *(const float4*)(src + 8 * q);
        const float4 v3 = *(const float4*)(src + 8 * q + 4);
        w[0]  = v0.x; w[1]  = v0.y; w[2]  = v0.z; w[3]  = v0.w;
        w[4]  = v1.x; w[5]  = v1.y; w[6]  = v1.z; w[7]  = v1.w;
        w[8]  = v2.x; w[9]  = v2.y; w[10] = v2.z; w[11] = v2.w;
        w[12] = v3.x; w[13] = v3.y; w[14] = v3.z; w[15] = v3.w;
    }
}

__global__ __launch_bounds__(256, 5)
void dwt5_kernel(const float* __restrict__ x, float* __restrict__ out)
{
    __shared__ float buf[8192];     // 32 KB: a1, then in-place a2/a3/a4
    const int r   = blockIdx.x;
    const int tid = threadIdx.x;

    const float* __restrict__ xr = x + (size_t)r * SLEN;
    const size_t frBase = (size_t)33554432 + (size_t)r * 8192;

    // ---- L1: x(16384) -> a1(8192), low only (d1 never output) ----
    for (int j = 0; j < 8; ++j) {
        const int q = tid + j * 256;          // group of 4 outputs
        float w[16];
        loadw16(xr, q, w);
        float4 a;
        a.x = dotH(w + 1); a.y = dotH(w + 3); a.z = dotH(w + 5); a.w = dotH(w + 7);
        *(float4*)(buf + 4 * q) = a;
    }
    __syncthreads();

    // ---- L2: a1(8192) -> a2(4096) in-place, d2(4096) -> Fg + FR ----
    {
        float* __restrict__ hi1 = out + (size_t)16777216 + (size_t)r * 4096;
        float* __restrict__ hi2 = out + frBase + 4096;
        float st[16];
        for (int j = 0; j < 4; ++j) {
            const int q = tid + j * 256;      // 0..1023
            float w[16];
            loadw16(buf, q, w);
            float4 d;
            d.x = dotG(w + 1); d.y = dotG(w + 3); d.z = dotG(w + 5); d.w = dotG(w + 7);
            *(float4*)(hi1 + 4 * q) = d;
            *(float4*)(hi2 + 4 * q) = d;
            st[4*j+0] = dotH(w + 1); st[4*j+1] = dotH(w + 3);
            st[4*j+2] = dotH(w + 5); st[4*j+3] = dotH(w + 7);
        }
        __syncthreads();
        for (int j = 0; j < 4; ++j) {
            const int q = tid + j * 256;
            *(float4*)(buf + 4 * q) = make_float4(st[4*j], st[4*j+1], st[4*j+2], st[4*j+3]);
        }
        __syncthreads();
    }

    // ---- L3: a2(4096) -> a3(2048) in-place, d3(2048) -> Fb + FR ----
    {
        float* __restrict__ hi1 = out + (size_t)8388608 + (size_t)r * 2048;
        float* __restrict__ hi2 = out + frBase + 2048;
        float st[8];
        for (int j = 0; j < 2; ++j) {
            const int q = tid + j * 256;      // 0..511
            float w[16];
            loadw16(buf, q, w);
            float4 d;
            d.x = dotG(w + 1); d.y = dotG(w + 3); d.z = dotG(w + 5); d.w = dotG(w + 7);
            *(float4*)(hi1 + 4 * q) = d;
            *(float4*)(hi2 + 4 * q) = d;
            st[4*j+0] = dotH(w + 1); st[4*j+1] = dotH(w + 3);
            st[4*j+2] = dotH(w + 5); st[4*j+3] = dotH(w + 7);
        }
        __syncthreads();
        for (int j = 0; j < 2; ++j) {
            const int q = tid + j * 256;
            *(float4*)(buf + 4 * q) = make_float4(st[4*j], st[4*j+1], st[4*j+2], st[4*j+3]);
        }
        __syncthreads();
    }

    // ---- L4: a3(2048) -> a4(1024) in-place, d4(1024) -> Fa + FR ----
    {
        float* __restrict__ hi1 = out + (size_t)4194304 + (size_t)r * 1024;
        float* __restrict__ hi2 = out + frBase + 1024;
        const int q = tid;                    // 0..255
        float w[16];
        loadw16(buf, q, w);
        float4 d;
        d.x = dotG(w + 1); d.y = dotG(w + 3); d.z = dotG(w + 5); d.w = dotG(w + 7);
        *(float4*)(hi1 + 4 * q) = d;
        *(float4*)(hi2 + 4 * q) = d;
        float4 a;
        a.x = dotH(w + 1); a.y = dotH(w + 3); a.z = dotH(w + 5); a.w = dotH(w + 7);
        __syncthreads();
        *(float4*)(buf + 4 * q) = a;
        __syncthreads();
    }

    // ---- L5: a4(1024) -> Fd(512) + Ft(512), both also to FR ----
    if (tid < 128) {
        const int q = tid;                    // 0..127
        float w[16];
        loadw16(buf, q, w);
        float4 a, d;
        a.x = dotH(w + 1); a.y = dotH(w + 3); a.z = dotH(w + 5); a.w = dotH(w + 7);
        d.x = dotG(w + 1); d.y = dotG(w + 3); d.z = dotG(w + 5); d.w = dotG(w + 7);
        *(float4*)(out + (size_t)r * 512 + 4 * q)                      = a;
        *(float4*)(out + frBase + 4 * q)                               = a;
        *(float4*)(out + (size_t)2097152 + (size_t)r * 512 + 4 * q)    = d;
        *(float4*)(out + frBase + 512 + 4 * q)                         = d;
    }
}

extern "C" void kernel_launch(void* const* d_in, const int* in_sizes, int n_in,
                              void* d_out, int out_size, void* d_ws, size_t ws_size,
                              hipStream_t stream) {
    const float* x = (const float*)d_in[0];
    float* out = (float*)d_out;
    dwt5_kernel<<<4096, 256, 0, stream>>>(x, out);
}

// Round 4
// 109.172 us; speedup vs baseline: 2.0304x; 1.0994x over previous
//
#include <hip/hip_runtime.h>

// 5-level Db4 DWT, rows of 16384 fp32, B*C = 4096 rows.
// Each row is split across TWO blocks (h = bid&1) with a redundant low-pass
// left-halo so the halves are independent: halo at a1/a2/a3/a4 = 120/56/24/8.
// out layout (flat, return order):
//   Fd  4096x512   @ 0
//   Ft  4096x512   @ 2097152
//   Fa  4096x1024  @ 4194304
//   Fb  4096x2048  @ 8388608
//   Fg  4096x4096  @ 16777216
//   FR  4096x8192  @ 33554432   (per-row: [Fd|Ft|Fa|Fb|Fg])

static constexpr int SLEN = 16384;

// Db4 filters are fixed (non-learnable) — hardcoded as literals.
__device__ __forceinline__ float dotH(const float* w) {
    float s =      -0.010597401785069032f * w[0];
    s = fmaf( 0.032883011666982945f, w[1], s);
    s = fmaf( 0.030841381835560764f, w[2], s);
    s = fmaf(-0.18703481171888114f,  w[3], s);
    s = fmaf(-0.02798376941698385f,  w[4], s);
    s = fmaf( 0.6308807679295904f,   w[5], s);
    s = fmaf( 0.7148465705529155f,   w[6], s);
    s = fmaf( 0.2303778133088964f,   w[7], s);
    return s;
}
// g[k] = (-1)^k * h[7-k]
__device__ __forceinline__ float dotG(const float* w) {
    float s =       0.2303778133088964f * w[0];
    s = fmaf(-0.7148465705529155f,   w[1], s);
    s = fmaf( 0.6308807679295904f,   w[2], s);
    s = fmaf( 0.02798376941698385f,  w[3], s);
    s = fmaf(-0.18703481171888114f,  w[4], s);
    s = fmaf(-0.030841381835560764f, w[5], s);
    s = fmaf( 0.032883011666982945f, w[6], s);
    s = fmaf( 0.010597401785069032f, w[7], s);
    return s;
}

// Load the 16-float window src[8q-8 .. 8q+7] for outputs n=4q..4q+3 of the
// next level (global group index q). q==0 takes the scalar reflect path.
__device__ __forceinline__ void loadw16(const float* __restrict__ src, int q, float* w) {
    if (q == 0) {
#pragma unroll
        for (int i = 0; i < 16; ++i) { int m = i - 8; m = (m < 0) ? -m : m; w[i] = src[m]; }
    } else {
        const float4 v0 = *(const float4*)(src + 8 * q - 8);
        const float4 v1 = *(const float4*)(src + 8 * q - 4);
        const float4 v2 = *(const float4*)(src + 8 * q);
        const float4 v3 = *(const float4*)(src + 8 * q + 4);
        w[0]  = v0.x; w[1]  = v0.y; w[2]  = v0.z; w[3]  = v0.w;
        w[4]  = v1.x; w[5]  = v1.y; w[6]  = v1.z; w[7]  = v1.w;
        w[8]  = v2.x; w[9]  = v2.y; w[10] = v2.z; w[11] = v2.w;
        w[12] = v3.x; w[13] = v3.y; w[14] = v3.z; w[15] = v3.w;
    }
}

__global__ __launch_bounds__(256, 6)
void dwt5_kernel(const float* __restrict__ x, float* __restrict__ out)
{
    __shared__ float buf[4224];     // 16.9 KB: a1-half(+halo), then in-place a2/a3/a4
    const int bid = blockIdx.x;
    const int r   = bid >> 1;       // row
    const int h   = bid & 1;        // half (0 = left, 1 = right)
    const int tid = threadIdx.x;

    const float* __restrict__ xr = x + (size_t)r * SLEN;
    const size_t frBase = (size_t)33554432 + (size_t)r * 8192;

    // Global approx index stored at buf[0], per level (left half: 0).
    const int A1s = h ? 3976 : 0;
    const int A2s = h ? 1992 : 0;
    const int A3s = h ? 1000 : 0;
    const int A4s = h ?  504 : 0;

    // ---- L1: x -> a1 (low only; d1 never output) ----
    {
        const int g1lo = A1s >> 2;            // 994 | 0
        const int g1hi = h ? 2048 : 1024;     // global group bound
#pragma unroll
        for (int jj = 0; jj < 5; ++jj) {
            const int g = g1lo + tid + jj * 256;
            if (g < g1hi) {
                float w[16];
                loadw16(xr, g, w);
                float4 a;
                a.x = dotH(w + 1); a.y = dotH(w + 3); a.z = dotH(w + 5); a.w = dotH(w + 7);
                *(float4*)(buf + 4 * g - A1s) = a;
            }
        }
    }
    __syncthreads();

    // ---- L2: a1 -> a2 (in-place, stash), d2 -> Fg + FR ----
    {
        const int g2lo = A2s >> 2;            // 498 | 0
        const int g2hi = h ? 1024 : 512;
        const int gd2  = h ? 512 : 0;         // first group with high-band output
        const float* src = buf - A1s;
        float* __restrict__ hi1 = out + (size_t)16777216 + (size_t)r * 4096;
        float* __restrict__ hi2 = out + frBase + 4096;
        float st[12];
#pragma unroll
        for (int jj = 0; jj < 3; ++jj) {
            const int g = g2lo + tid + jj * 256;
            if (g < g2hi) {
                float w[16];
                loadw16(src, g, w);
                st[4*jj+0] = dotH(w + 1); st[4*jj+1] = dotH(w + 3);
                st[4*jj+2] = dotH(w + 5); st[4*jj+3] = dotH(w + 7);
                if (g >= gd2) {
                    float4 d;
                    d.x = dotG(w + 1); d.y = dotG(w + 3); d.z = dotG(w + 5); d.w = dotG(w + 7);
                    *(float4*)(hi1 + 4 * g) = d;
                    *(float4*)(hi2 + 4 * g) = d;
                }
            }
        }
        __syncthreads();
#pragma unroll
        for (int jj = 0; jj < 3; ++jj) {
            const int g = g2lo + tid + jj * 256;
            if (g < g2hi)
                *(float4*)(buf + 4 * g - A2s) =
                    make_float4(st[4*jj], st[4*jj+1], st[4*jj+2], st[4*jj+3]);
        }
        __syncthreads();
    }

    // ---- L3: a2 -> a3 (in-place, stash), d3 -> Fb + FR ----
    {
        const int g3lo = A3s >> 2;            // 250 | 0
        const int g3hi = h ? 512 : 256;
        const int gd3  = h ? 256 : 0;
        const float* src = buf - A2s;
        float* __restrict__ hi1 = out + (size_t)8388608 + (size_t)r * 2048;
        float* __restrict__ hi2 = out + frBase + 2048;
        float st[8];
#pragma unroll
        for (int jj = 0; jj < 2; ++jj) {
            const int g = g3lo + tid + jj * 256;
            if (g < g3hi) {
                float w[16];
                loadw16(src, g, w);
                st[4*jj+0] = dotH(w + 1); st[4*jj+1] = dotH(w + 3);
                st[4*jj+2] = dotH(w + 5); st[4*jj+3] = dotH(w + 7);
                if (g >= gd3) {
                    float4 d;
                    d.x = dotG(w + 1); d.y = dotG(w + 3); d.z = dotG(w + 5); d.w = dotG(w + 7);
                    *(float4*)(hi1 + 4 * g) = d;
                    *(float4*)(hi2 + 4 * g) = d;
                }
            }
        }
        __syncthreads();
#pragma unroll
        for (int jj = 0; jj < 2; ++jj) {
            const int g = g3lo + tid + jj * 256;
            if (g < g3hi)
                *(float4*)(buf + 4 * g - A3s) =
                    make_float4(st[4*jj], st[4*jj+1], st[4*jj+2], st[4*jj+3]);
        }
        __syncthreads();
    }

    // ---- L4: a3 -> a4 (in-place, stash), d4 -> Fa + FR ----
    {
        const int g4lo = A4s >> 2;            // 126 | 0
        const int g4hi = h ? 256 : 128;
        const int gd4  = h ? 128 : 0;
        const float* src = buf - A3s;
        float* __restrict__ hi1 = out + (size_t)4194304 + (size_t)r * 1024;
        float* __restrict__ hi2 = out + frBase + 1024;
        float4 a = make_float4(0.f, 0.f, 0.f, 0.f);
        const int g = g4lo + tid;
        const bool act = (g < g4hi);
        if (act) {
            float w[16];
            loadw16(src, g, w);
            a.x = dotH(w + 1); a.y = dotH(w + 3); a.z = dotH(w + 5); a.w = dotH(w + 7);
            if (g >= gd4) {
                float4 d;
                d.x = dotG(w + 1); d.y = dotG(w + 3); d.z = dotG(w + 5); d.w = dotG(w + 7);
                *(float4*)(hi1 + 4 * g) = d;
                *(float4*)(hi2 + 4 * g) = d;
            }
        }
        __syncthreads();
        if (act)
            *(float4*)(buf + 4 * g - A4s) = a;
        __syncthreads();
    }

    // ---- L5: a4 -> Fd + Ft, both also to FR ----
    {
        const int g5lo = h ? 64 : 0;
        const int g = g5lo + tid;
        if (g < g5lo + 64) {                  // tid < 64
            const float* src = buf - A4s;
            float w[16];
            loadw16(src, g, w);
            float4 a, d;
            a.x = dotH(w + 1); a.y = dotH(w + 3); a.z = dotH(w + 5); a.w = dotH(w + 7);
            d.x = dotG(w + 1); d.y = dotG(w + 3); d.z = dotG(w + 5); d.w = dotG(w + 7);
            *(float4*)(out + (size_t)r * 512 + 4 * g)                   = a;
            *(float4*)(out + frBase + 4 * g)                            = a;
            *(float4*)(out + (size_t)2097152 + (size_t)r * 512 + 4 * g) = d;
            *(float4*)(out + frBase + 512 + 4 * g)                      = d;
        }
    }
}

extern "C" void kernel_launch(void* const* d_in, const int* in_sizes, int n_in,
                              void* d_out, int out_size, void* d_ws, size_t ws_size,
                              hipStream_t stream) {
    const float* x = (const float*)d_in[0];
    float* out = (float*)d_out;
    dwt5_kernel<<<8192, 256, 0, stream>>>(x, out);
}

// Round 6
// 90.548 us; speedup vs baseline: 2.4480x; 1.2057x over previous
//
#include <hip/hip_runtime.h>

// 5-level Db4 DWT, rows of 16384 fp32, B*C = 4096 rows.
// Each row is split across TWO blocks (h = bid&1) with a redundant low-pass
// left-halo so the halves are independent.
// LDS uses disjoint per-level regions -> ONE barrier per level (4 total),
// and barriers wait on LDS ops only (global NT stores drain in background).
// out layout (flat, return order):
//   Fd  4096x512   @ 0
//   Ft  4096x512   @ 2097152
//   Fa  4096x1024  @ 4194304
//   Fb  4096x2048  @ 8388608
//   Fg  4096x4096  @ 16777216
//   FR  4096x8192  @ 33554432   (per-row: [Fd|Ft|Fa|Fb|Fg])

static constexpr int SLEN = 16384;

typedef float f32x4 __attribute__((ext_vector_type(4)));

// Db4 filters are fixed (non-learnable) — hardcoded as literals.
__device__ __forceinline__ float dotH(const float* w) {
    float s =      -0.010597401785069032f * w[0];
    s = fmaf( 0.032883011666982945f, w[1], s);
    s = fmaf( 0.030841381835560764f, w[2], s);
    s = fmaf(-0.18703481171888114f,  w[3], s);
    s = fmaf(-0.02798376941698385f,  w[4], s);
    s = fmaf( 0.6308807679295904f,   w[5], s);
    s = fmaf( 0.7148465705529155f,   w[6], s);
    s = fmaf( 0.2303778133088964f,   w[7], s);
    return s;
}
// g[k] = (-1)^k * h[7-k]
__device__ __forceinline__ float dotG(const float* w) {
    float s =       0.2303778133088964f * w[0];
    s = fmaf(-0.7148465705529155f,   w[1], s);
    s = fmaf( 0.6308807679295904f,   w[2], s);
    s = fmaf( 0.02798376941698385f,  w[3], s);
    s = fmaf(-0.18703481171888114f,  w[4], s);
    s = fmaf(-0.030841381835560764f, w[5], s);
    s = fmaf( 0.032883011666982945f, w[6], s);
    s = fmaf( 0.010597401785069032f, w[7], s);
    return s;
}

// Load the 16-float window src[8q-8 .. 8q+7] for outputs n=4q..4q+3.
// q==0 takes the scalar reflect path (index m<0 -> -m).
__device__ __forceinline__ void loadw16(const float* __restrict__ src, int q, float* w) {
    if (q == 0) {
#pragma unroll
        for (int i = 0; i < 16; ++i) { int m = i - 8; m = (m < 0) ? -m : m; w[i] = src[m]; }
    } else {
        const float4 v0 = *(const float4*)(src + 8 * q - 8);
        const float4 v1 = *(const float4*)(src + 8 * q - 4);
        const float4 v2 = *(const float4*)(src + 8 * q);
        const float4 v3 = *(const float4*)(src + 8 * q + 4);
        w[0]  = v0.x; w[1]  = v0.y; w[2]  = v0.z; w[3]  = v0.w;
        w[4]  = v1.x; w[5]  = v1.y; w[6]  = v1.z; w[7]  = v1.w;
        w[8]  = v2.x; w[9]  = v2.y; w[10] = v2.z; w[11] = v2.w;
        w[12] = v3.x; w[13] = v3.y; w[14] = v3.z; w[15] = v3.w;
    }
}

__device__ __forceinline__ void ntst4(float* p, float a0, float a1, float a2, float a3) {
    f32x4 v; v.x = a0; v.y = a1; v.z = a2; v.w = a3;
    __builtin_nontemporal_store(v, (f32x4*)p);
}

// Barrier that waits on LDS ops only; outstanding global (NT) stores keep
// draining in the background. Memory-clobber asm on both sides pins ordering.
__device__ __forceinline__ void barrier_lds() {
    asm volatile("s_waitcnt lgkmcnt(0)" ::: "memory");
    __builtin_amdgcn_s_barrier();
    asm volatile("" ::: "memory");
}

__global__ __launch_bounds__(256, 6)
void dwt5_kernel(const float* __restrict__ x, float* __restrict__ out)
{
    // Region map (floats):
    //   a1: [0 .. 4216)       (h=1 worst case; h=0 uses [0..4096))
    //   a2: [4224 .. 6328)    REG2
    //   a3: [0 .. 1048)       (overwrites dead a1 after barrier)
    //   a4: [2048 .. 2568)    REG4 (disjoint from a3 and a2)
    __shared__ float buf[6336];   // 25.3 KB -> 6 blocks/CU
    const int bid = blockIdx.x;
    const int r   = bid >> 1;     // row
    const int h   = bid & 1;      // half (0 = left, 1 = right)
    const int tid = threadIdx.x;

    const float* __restrict__ xr = x + (size_t)r * SLEN;
    const size_t frBase = (size_t)33554432 + (size_t)r * 8192;

    // Global approx index stored at region offset 0, per level (left half: 0).
    const int A1s = h ? 3976 : 0;
    const int A2s = h ? 1992 : 0;
    const int A3s = h ? 1000 : 0;
    const int A4s = h ?  504 : 0;
    constexpr int REG2 = 4224;
    constexpr int REG4 = 2048;

    // ---- L1: x -> a1 (low only; d1 never output) ----
    {
        const int g1lo = A1s >> 2;            // 994 | 0
        const int g1hi = h ? 2048 : 1024;
#pragma unroll
        for (int jj = 0; jj < 5; ++jj) {
            const int g = g1lo + tid + jj * 256;
            if (g < g1hi) {
                float w[16];
                loadw16(xr, g, w);
                float4 a = make_float4(dotH(w + 1), dotH(w + 3), dotH(w + 5), dotH(w + 7));
                *(float4*)(buf + 4 * g - A1s) = a;
            }
        }
    }
    barrier_lds();

    // ---- L2: a1 -> a2 (disjoint region), d2 -> Fg + FR ----
    {
        const int g2lo = A2s >> 2;            // 498 | 0
        const int g2hi = h ? 1024 : 512;
        const int gd   = h ? 512 : 0;
        const float* src = buf - A1s;
        float* __restrict__ hi1 = out + (size_t)16777216 + (size_t)r * 4096;
        float* __restrict__ hi2 = out + frBase + 4096;
#pragma unroll
        for (int jj = 0; jj < 3; ++jj) {
            const int g = g2lo + tid + jj * 256;
            if (g < g2hi) {
                float w[16];
                loadw16(src, g, w);
                float4 a = make_float4(dotH(w + 1), dotH(w + 3), dotH(w + 5), dotH(w + 7));
                *(float4*)(buf + REG2 + 4 * g - A2s) = a;
                if (g >= gd) {
                    ntst4(hi1 + 4 * g, dotG(w + 1), dotG(w + 3), dotG(w + 5), dotG(w + 7));
                    ntst4(hi2 + 4 * g, dotG(w + 1), dotG(w + 3), dotG(w + 5), dotG(w + 7));
                }
            }
        }
    }
    barrier_lds();

    // ---- L3: a2 -> a3 (into dead a1 area), d3 -> Fb + FR ----
    {
        const int g3lo = A3s >> 2;            // 250 | 0
        const int g3hi = h ? 512 : 256;
        const int gd   = h ? 256 : 0;
        const float* src = buf + REG2 - A2s;
        float* __restrict__ hi1 = out + (size_t)8388608 + (size_t)r * 2048;
        float* __restrict__ hi2 = out + frBase + 2048;
#pragma unroll
        for (int jj = 0; jj < 2; ++jj) {
            const int g = g3lo + tid + jj * 256;
            if (g < g3hi) {
                float w[16];
                loadw16(src, g, w);
                float4 a = make_float4(dotH(w + 1), dotH(w + 3), dotH(w + 5), dotH(w + 7));
                *(float4*)(buf + 4 * g - A3s) = a;
                if (g >= gd) {
                    ntst4(hi1 + 4 * g, dotG(w + 1), dotG(w + 3), dotG(w + 5), dotG(w + 7));
                    ntst4(hi2 + 4 * g, dotG(w + 1), dotG(w + 3), dotG(w + 5), dotG(w + 7));
                }
            }
        }
    }
    barrier_lds();

    // ---- L4: a3 -> a4 (REG4, disjoint), d4 -> Fa + FR ----
    {
        const int g4lo = A4s >> 2;            // 126 | 0
        const int g4hi = h ? 256 : 128;
        const int gd   = h ? 128 : 0;
        const float* src = buf - A3s;
        float* __restrict__ hi1 = out + (size_t)4194304 + (size_t)r * 1024;
        float* __restrict__ hi2 = out + frBase + 1024;
        const int g = g4lo + tid;
        if (g < g4hi) {
            float w[16];
            loadw16(src, g, w);
            float4 a = make_float4(dotH(w + 1), dotH(w + 3), dotH(w + 5), dotH(w + 7));
            *(float4*)(buf + REG4 + 4 * g - A4s) = a;
            if (g >= gd) {
                ntst4(hi1 + 4 * g, dotG(w + 1), dotG(w + 3), dotG(w + 5), dotG(w + 7));
                ntst4(hi2 + 4 * g, dotG(w + 1), dotG(w + 3), dotG(w + 5), dotG(w + 7));
            }
        }
    }
    barrier_lds();

    // ---- L5: a4 -> Fd + Ft, both also to FR ----
    {
        const int g5lo = h ? 64 : 0;
        const int g = g5lo + tid;
        if (g < g5lo + 64) {                  // tid < 64
            const float* src = buf + REG4 - A4s;
            float w[16];
            loadw16(src, g, w);
            const float a0 = dotH(w + 1), a1 = dotH(w + 3), a2 = dotH(w + 5), a3 = dotH(w + 7);
            const float d0 = dotG(w + 1), d1 = dotG(w + 3), d2 = dotG(w + 5), d3 = dotG(w + 7);
            ntst4(out + (size_t)r * 512 + 4 * g,                   a0, a1, a2, a3);
            ntst4(out + frBase + 4 * g,                            a0, a1, a2, a3);
            ntst4(out + (size_t)2097152 + (size_t)r * 512 + 4 * g, d0, d1, d2, d3);
            ntst4(out + frBase + 512 + 4 * g,                      d0, d1, d2, d3);
        }
    }
}

extern "C" void kernel_launch(void* const* d_in, const int* in_sizes, int n_in,
                              void* d_out, int out_size, void* d_ws, size_t ws_size,
                              hipStream_t stream) {
    const float* x = (const float*)d_in[0];
    float* out = (float*)d_out;
    dwt5_kernel<<<8192, 256, 0, stream>>>(x, out);
}

// Round 7
// 87.533 us; speedup vs baseline: 2.5323x; 1.0344x over previous
//
#include <hip/hip_runtime.h>

// 5-level Db4 DWT, rows of 16384 fp32, B*C = 4096 rows.
// Each row is split across TWO blocks (h = bid&1) with a redundant low-pass
// left-halo so the halves are independent.
// LDS: disjoint per-level regions, ONE LDS-only barrier per level (4 total),
// XOR-swizzled float4 slots (slot' = slot ^ ((slot>>3)&7)) so the stride-32B
// window reads are bank-conflict-free (writes remain conflict-free).
// out layout (flat, return order):
//   Fd  4096x512   @ 0
//   Ft  4096x512   @ 2097152
//   Fa  4096x1024  @ 4194304
//   Fb  4096x2048  @ 8388608
//   Fg  4096x4096  @ 16777216
//   FR  4096x8192  @ 33554432   (per-row: [Fd|Ft|Fa|Fb|Fg])

static constexpr int SLEN = 16384;

typedef float f32x4 __attribute__((ext_vector_type(4)));

// Swizzled float offset for a float4-aligned region-relative offset f (>=0).
__device__ __forceinline__ int swz4(int f) {
    const int s = f >> 2;
    return (s ^ ((s >> 3) & 7)) << 2;
}
// Swizzled float offset for an arbitrary region-relative offset f (>=0).
__device__ __forceinline__ int swz1(int f) {
    const int s = f >> 2;
    return (((s ^ ((s >> 3) & 7)) << 2) | (f & 3));
}

// Db4 filters are fixed (non-learnable) — hardcoded as literals.
__device__ __forceinline__ float dotH(const float* w) {
    float s =      -0.010597401785069032f * w[0];
    s = fmaf( 0.032883011666982945f, w[1], s);
    s = fmaf( 0.030841381835560764f, w[2], s);
    s = fmaf(-0.18703481171888114f,  w[3], s);
    s = fmaf(-0.02798376941698385f,  w[4], s);
    s = fmaf( 0.6308807679295904f,   w[5], s);
    s = fmaf( 0.7148465705529155f,   w[6], s);
    s = fmaf( 0.2303778133088964f,   w[7], s);
    return s;
}
// g[k] = (-1)^k * h[7-k]
__device__ __forceinline__ float dotG(const float* w) {
    float s =       0.2303778133088964f * w[0];
    s = fmaf(-0.7148465705529155f,   w[1], s);
    s = fmaf( 0.6308807679295904f,   w[2], s);
    s = fmaf( 0.02798376941698385f,  w[3], s);
    s = fmaf(-0.18703481171888114f,  w[4], s);
    s = fmaf(-0.030841381835560764f, w[5], s);
    s = fmaf( 0.032883011666982945f, w[6], s);
    s = fmaf( 0.010597401785069032f, w[7], s);
    return s;
}

// GLOBAL window load: 16 floats x[8q-8 .. 8q+7]; q==0 reflect path.
__device__ __forceinline__ void loadw16g(const float* __restrict__ src, int q, float* w) {
    if (q == 0) {
#pragma unroll
        for (int i = 0; i < 16; ++i) { int m = i - 8; m = (m < 0) ? -m : m; w[i] = src[m]; }
    } else {
        const float4 v0 = *(const float4*)(src + 8 * q - 8);
        const float4 v1 = *(const float4*)(src + 8 * q - 4);
        const float4 v2 = *(const float4*)(src + 8 * q);
        const float4 v3 = *(const float4*)(src + 8 * q + 4);
        w[0]  = v0.x; w[1]  = v0.y; w[2]  = v0.z; w[3]  = v0.w;
        w[4]  = v1.x; w[5]  = v1.y; w[6]  = v1.z; w[7]  = v1.w;
        w[8]  = v2.x; w[9]  = v2.y; w[10] = v2.z; w[11] = v2.w;
        w[12] = v3.x; w[13] = v3.y; w[14] = v3.z; w[15] = v3.w;
    }
}

// SWIZZLED LDS window load: 16 floats at region-relative offsets foff..foff+15
// (foff multiple of 4, >= 0). base = region origin (32-float aligned).
__device__ __forceinline__ void lw16s(const float* __restrict__ base, int foff, float* w) {
#pragma unroll
    for (int j = 0; j < 4; ++j) {
        const float4 v = *(const float4*)(base + swz4(foff + 4 * j));
        w[4*j+0] = v.x; w[4*j+1] = v.y; w[4*j+2] = v.z; w[4*j+3] = v.w;
    }
}
// Reflect path (global q==0, only on h==0 where the region shift is 0).
__device__ __forceinline__ void lw16s_q0(const float* __restrict__ base, float* w) {
#pragma unroll
    for (int i = 0; i < 16; ++i) { int m = i - 8; m = (m < 0) ? -m : m; w[i] = base[swz1(m)]; }
}

__device__ __forceinline__ void ntst4(float* p, float a0, float a1, float a2, float a3) {
    f32x4 v; v.x = a0; v.y = a1; v.z = a2; v.w = a3;
    __builtin_nontemporal_store(v, (f32x4*)p);
}

// Barrier that waits on LDS ops only; outstanding global (NT) stores keep
// draining in the background.
__device__ __forceinline__ void barrier_lds() {
    asm volatile("s_waitcnt lgkmcnt(0)" ::: "memory");
    __builtin_amdgcn_s_barrier();
    asm volatile("" ::: "memory");
}

__global__ __launch_bounds__(256, 6)
void dwt5_kernel(const float* __restrict__ x, float* __restrict__ out)
{
    // Region map (floats, all origins 32-float aligned; extents verified
    // non-overlapping under the within-group swizzle):
    //   a1: buf+0    [0 .. 4224)
    //   a2: buf+4224 [0 .. 2112)   REG2
    //   a3: buf+0    [0 .. 1056)   (overwrites dead a1 after barrier)
    //   a4: buf+2048 [0 .. 544)    REG4
    __shared__ float buf[6336];   // 25.3 KB -> 6 blocks/CU
    const int bid = blockIdx.x;
    const int r   = bid >> 1;     // row
    const int h   = bid & 1;      // half (0 = left, 1 = right)
    const int tid = threadIdx.x;

    const float* __restrict__ xr = x + (size_t)r * SLEN;
    const size_t frBase = (size_t)33554432 + (size_t)r * 8192;

    // Region shift per level (left half: 0).
    const int A1s = h ? 3976 : 0;
    const int A2s = h ? 1992 : 0;
    const int A3s = h ? 1000 : 0;
    const int A4s = h ?  504 : 0;
    constexpr int REG2 = 4224;
    constexpr int REG4 = 2048;

    // ---- L1: x -> a1 (low only; d1 never output) ----
    {
        const int g1lo = A1s >> 2;            // 994 | 0
        const int g1hi = h ? 2048 : 1024;
#pragma unroll
        for (int jj = 0; jj < 5; ++jj) {
            const int g = g1lo + tid + jj * 256;
            if (g < g1hi) {
                float w[16];
                loadw16g(xr, g, w);
                const float a0 = dotH(w + 1), a1 = dotH(w + 3), a2 = dotH(w + 5), a3 = dotH(w + 7);
                *(float4*)(buf + swz4(4 * g - A1s)) = make_float4(a0, a1, a2, a3);
            }
        }
    }
    barrier_lds();

    // ---- L2: a1 -> a2 (REG2), d2 -> Fg + FR ----
    {
        const int g2lo = A2s >> 2;            // 498 | 0
        const int g2hi = h ? 1024 : 512;
        const int gd   = h ? 512 : 0;
        float* __restrict__ hi1 = out + (size_t)16777216 + (size_t)r * 4096;
        float* __restrict__ hi2 = out + frBase + 4096;
#pragma unroll
        for (int jj = 0; jj < 3; ++jj) {
            const int g = g2lo + tid + jj * 256;
            if (g < g2hi) {
                float w[16];
                if (g == 0) lw16s_q0(buf, w);
                else        lw16s(buf, 8 * g - 8 - A1s, w);
                const float a0 = dotH(w + 1), a1 = dotH(w + 3), a2 = dotH(w + 5), a3 = dotH(w + 7);
                *(float4*)(buf + REG2 + swz4(4 * g - A2s)) = make_float4(a0, a1, a2, a3);
                if (g >= gd) {
                    const float d0 = dotG(w + 1), d1 = dotG(w + 3), d2 = dotG(w + 5), d3 = dotG(w + 7);
                    ntst4(hi1 + 4 * g, d0, d1, d2, d3);
                    ntst4(hi2 + 4 * g, d0, d1, d2, d3);
                }
            }
        }
    }
    barrier_lds();

    // ---- L3: a2 -> a3 (into dead a1 area), d3 -> Fb + FR ----
    {
        const int g3lo = A3s >> 2;            // 250 | 0
        const int g3hi = h ? 512 : 256;
        const int gd   = h ? 256 : 0;
        float* __restrict__ hi1 = out + (size_t)8388608 + (size_t)r * 2048;
        float* __restrict__ hi2 = out + frBase + 2048;
#pragma unroll
        for (int jj = 0; jj < 2; ++jj) {
            const int g = g3lo + tid + jj * 256;
            if (g < g3hi) {
                float w[16];
                if (g == 0) lw16s_q0(buf + REG2, w);
                else        lw16s(buf + REG2, 8 * g - 8 - A2s, w);
                const float a0 = dotH(w + 1), a1 = dotH(w + 3), a2 = dotH(w + 5), a3 = dotH(w + 7);
                *(float4*)(buf + swz4(4 * g - A3s)) = make_float4(a0, a1, a2, a3);
                if (g >= gd) {
                    const float d0 = dotG(w + 1), d1 = dotG(w + 3), d2 = dotG(w + 5), d3 = dotG(w + 7);
                    ntst4(hi1 + 4 * g, d0, d1, d2, d3);
                    ntst4(hi2 + 4 * g, d0, d1, d2, d3);
                }
            }
        }
    }
    barrier_lds();

    // ---- L4: a3 -> a4 (REG4), d4 -> Fa + FR ----
    {
        const int g4lo = A4s >> 2;            // 126 | 0
        const int g4hi = h ? 256 : 128;
        const int gd   = h ? 128 : 0;
        float* __restrict__ hi1 = out + (size_t)4194304 + (size_t)r * 1024;
        float* __restrict__ hi2 = out + frBase + 1024;
        const int g = g4lo + tid;
        if (g < g4hi) {
            float w[16];
            if (g == 0) lw16s_q0(buf, w);
            else        lw16s(buf, 8 * g - 8 - A3s, w);
            const float a0 = dotH(w + 1), a1 = dotH(w + 3), a2 = dotH(w + 5), a3 = dotH(w + 7);
            *(float4*)(buf + REG4 + swz4(4 * g - A4s)) = make_float4(a0, a1, a2, a3);
            if (g >= gd) {
                const float d0 = dotG(w + 1), d1 = dotG(w + 3), d2 = dotG(w + 5), d3 = dotG(w + 7);
                ntst4(hi1 + 4 * g, d0, d1, d2, d3);
                ntst4(hi2 + 4 * g, d0, d1, d2, d3);
            }
        }
    }
    barrier_lds();

    // ---- L5: a4 -> Fd + Ft, both also to FR ----
    {
        const int g5lo = h ? 64 : 0;
        const int g = g5lo + tid;
        if (g < g5lo + 64) {                  // tid < 64
            float w[16];
            if (g == 0) lw16s_q0(buf + REG4, w);
            else        lw16s(buf + REG4, 8 * g - 8 - A4s, w);
            const float a0 = dotH(w + 1), a1 = dotH(w + 3), a2 = dotH(w + 5), a3 = dotH(w + 7);
            const float d0 = dotG(w + 1), d1 = dotG(w + 3), d2 = dotG(w + 5), d3 = dotG(w + 7);
            ntst4(out + (size_t)r * 512 + 4 * g,                   a0, a1, a2, a3);
            ntst4(out + frBase + 4 * g,                            a0, a1, a2, a3);
            ntst4(out + (size_t)2097152 + (size_t)r * 512 + 4 * g, d0, d1, d2, d3);
            ntst4(out + frBase + 512 + 4 * g,                      d0, d1, d2, d3);
        }
    }
}

extern "C" void kernel_launch(void* const* d_in, const int* in_sizes, int n_in,
                              void* d_out, int out_size, void* d_ws, size_t ws_size,
                              hipStream_t stream) {
    const float* x = (const float*)d_in[0];
    float* out = (float*)d_out;
    dwt5_kernel<<<8192, 256, 0, stream>>>(x, out);
}